// Round 8
// baseline (640.675 us; speedup 1.0000x reference)
//
#include <hip/hip_runtime.h>
#include <stdint.h>

typedef __bf16 bf16x8 __attribute__((ext_vector_type(8)));
typedef float f32x4 __attribute__((ext_vector_type(4)));

__device__ __forceinline__ float b2f(unsigned short u){
  unsigned int t = ((unsigned int)u) << 16;
  return __builtin_bit_cast(float, t);
}
__device__ __forceinline__ unsigned short f2b(float f){
  unsigned int x = __builtin_bit_cast(unsigned int, f);
  x = x + 0x7FFFu + ((x >> 16) & 1u);
  return (unsigned short)(x >> 16);
}
// spread 8 bits -> 8 packed bf16 {0.0,1.0} (element j = bit j)
__device__ __forceinline__ void spread8(unsigned int B, unsigned int w[4]){
  unsigned int m = __umul24(B, 0x8001u);
  w[0] = __umul24(m & 0x00010001u, 0x3F80u);
  w[1] = __umul24(m & 0x00040004u, 0x0FE0u);
  w[2] = __umul24(m & 0x00100010u, 0x03F8u);
  w[3] = __umul24(m & 0x00400040u, 0x00FEu);
}
__device__ __forceinline__ float fsig(float x){ return 1.f/(1.f + __expf(-x)); }
__device__ __forceinline__ float ftanh(float x){ return 1.f - 2.f/(__expf(2.f*x) + 1.f); }

// device barrier v2 (R7-verified): sense-reversing, RELAXED agent-scope spin,
// single RELEASE at arrive + single ACQUIRE at exit. 256 blocks, 1/CU co-resident.
__device__ __forceinline__ void gbar(int* bar){
  __syncthreads();
  if (threadIdx.x == 0){
    int g = __hip_atomic_load(&bar[1], __ATOMIC_RELAXED, __HIP_MEMORY_SCOPE_AGENT);
    int a = __hip_atomic_fetch_add(&bar[0], 1, __ATOMIC_RELEASE, __HIP_MEMORY_SCOPE_AGENT);
    if (a == 255){
      __hip_atomic_store(&bar[0], 0, __ATOMIC_RELAXED, __HIP_MEMORY_SCOPE_AGENT);
      __hip_atomic_fetch_add(&bar[1], 1, __ATOMIC_RELEASE, __HIP_MEMORY_SCOPE_AGENT);
    } else {
      int it = 0;
      while (__hip_atomic_load(&bar[1], __ATOMIC_RELAXED, __HIP_MEMORY_SCOPE_AGENT) == g){
        if (++it > 48) __builtin_amdgcn_s_sleep(1);
      }
    }
    (void)__hip_atomic_load(&bar[1], __ATOMIC_ACQUIRE, __HIP_MEMORY_SCOPE_AGENT);
  }
  __syncthreads();
}

// ---- prep: dtype-vote + convert all weights to canonical bf16 + zero deg/seg/cnt/bar ----
__global__ void k_prep(const void* s_msgW, const void* s_msgb, const void* s_wih,
                       const void* s_whh, const void* s_bih, const void* s_bhh,
                       const void* s_poolW, const void* s_poolb,
                       const unsigned short* __restrict__ aemb_u16,
                       unsigned short* __restrict__ cw,
                       int* __restrict__ deg, float* __restrict__ seg,
                       float* __restrict__ cnt, int* __restrict__ flag){
  int b = blockIdx.x, t = threadIdx.x;
  unsigned int uu = aemb_u16[2*t];
  int e = (int)((uu >> 7) & 0xFF);
  unsigned long long vote = __ballot(e >= 100 && e <= 127);
  int isb = (__popcll(vote) > 32) ? 1 : 0;
  if (b < 1771){
    int id = b*256 + t;
    if (id < 453248){
      const void* src; int off;
      if      (id < 163840){ src = s_msgW;  off = id; }
      else if (id < 166400){ src = s_msgb;  off = id - 163840; }
      else if (id < 412160){ src = s_wih;   off = id - 166400; }
      else if (id < 442880){ src = s_whh;   off = id - 412160; }
      else if (id < 443840){ src = s_bih;   off = id - 442880; }
      else if (id < 444800){ src = s_bhh;   off = id - 443840; }
      else if (id < 452992){ src = s_poolW; off = id - 444800; }
      else                 { src = s_poolb; off = id - 452992; }
      cw[id] = isb ? ((const unsigned short*)src)[off]
                   : f2b(((const float*)src)[off]);
    }
  } else {
    int id2 = (b - 1771)*256 + t;
    if (id2 < 8192){ deg[id2] = 0; seg[id2] = 0.f; }
    if (id2 < 256) cnt[id2] = 0.f;
    if (b == 1771 && t == 0){ flag[0] = isb; flag[4] = 0; flag[5] = 0; }
  }
}

// ---- fold HIDDEN dim (R6-verified): Vcat[d] = [wih@W1 | wih@W2] (96x64 bf16),
// bW[d] = msgb@wih^T (96 f32). grid 40 = 10 layers x 4 quarters; 256 threads.
__global__ void k_fuse(const unsigned short* __restrict__ cw,
                       unsigned short* __restrict__ vcat, float* __restrict__ bwv){
  int d = blockIdx.x >> 2, quarter = blockIdx.x & 3;
  const unsigned short* msgW = cw + (size_t)d*16384;            // [256][64]
  const unsigned short* msgb = cw + 163840 + d*256;             // [256]
  const unsigned short* wih  = cw + 166400 + (size_t)d*24576;   // [96][256]
  int t = threadIdx.x;
  #pragma unroll
  for (int i=0;i<6;i++){
    int idx = quarter*1536 + i*256 + t;     // [0,6144)
    int j = idx >> 6, e = idx & 63;
    const unsigned short* wr = wih + j*256;
    const unsigned short* wc = msgW + e;
    float acc = 0.f;
    for (int k=0;k<256;k++)
      acc += b2f(wr[k]) * b2f(wc[k*64]);
    vcat[(size_t)d*6144 + idx] = f2b(acc);
  }
  if (quarter == 0 && t < 96){
    const unsigned short* wr = wih + t*256;
    float acc = 0.f;
    for (int k=0;k<256;k++) acc += b2f(msgb[k]) * b2f(wr[k]);
    bwv[d*96 + t] = acc;
  }
}

// ---- pack adjacency into 16x16x32-A-fragment bit layout + degrees (r3-verified) ----
__global__ void k_pack(const int* __restrict__ adj, unsigned int* __restrict__ mask3,
                       int* __restrict__ deg){
  int tid = blockIdx.x*256 + threadIdx.x;    // 2,097,152
  int rb  = tid >> 12;
  int rem = tid & 4095;
  int kgg = rem >> 6;
  int L   = rem & 63;
  int lc = L & 15, q = L >> 4;
  int row = rb*16 + lc;
  const int4* p4 = (const int4*)(adj + (size_t)row*8192 + kgg*128 + q*8);
  unsigned int dw = 0; int pc = 0;
  #pragma unroll
  for (int s=0;s<4;s++){
    int4 u = p4[s*8];
    int4 v = p4[s*8 + 1];
    unsigned int b = (unsigned int)(u.x > 0)
                   | ((unsigned int)(u.y > 0) << 1)
                   | ((unsigned int)(u.z > 0) << 2)
                   | ((unsigned int)(u.w > 0) << 3)
                   | ((unsigned int)(v.x > 0) << 4)
                   | ((unsigned int)(v.y > 0) << 5)
                   | ((unsigned int)(v.z > 0) << 6)
                   | ((unsigned int)(v.w > 0) << 7);
    dw |= b << (8*s);
    pc += __popc(b);
  }
  mask3[tid] = dw;
  pc += __shfl_xor(pc, 16);
  pc += __shfl_xor(pc, 32);
  if (q == 0) atomicAdd(deg + row, pc);
}

// ---- merged bond-embedding + atom-embedding ----
__global__ void k_be(const int* __restrict__ af, const void* __restrict__ araw,
                     const int* __restrict__ bft, const void* __restrict__ braw,
                     const int* __restrict__ flag,
                     float* __restrict__ hf32, uint4* __restrict__ hfrag,
                     unsigned short* __restrict__ outB16, float* __restrict__ outB32){
  int b = blockIdx.x, t = threadIdx.x;
  if (b >= 512){
    int id = (b - 512)*512 + t;            // [0, 1048576)
    int e = id >> 5, c = id & 31;
    int idx = bft[e]*32 + c;
    if (flag[0]) outB16[id] = ((const unsigned short*)braw)[idx];
    else         outB32[id] = ((const float*)braw)[idx];
    return;
  }
  __shared__ __align__(16) float sh[512];
  int r = t >> 5, c = t & 31;
  int row = b*16 + r;
  int idx = af[row]*32 + c;
  float f;
  if (flag[0]) f = b2f(((const unsigned short*)araw)[idx]);
  else         f = ((const float*)araw)[idx];
  hf32[row*32 + c] = f;
  sh[r*32 + c] = f;
  __syncthreads();
  if (t < 64){
    int nt = t >> 5, Lq = t & 31;
    int ks32 = b >> 1, half = b & 1;
    int col = nt*16 + (Lq & 15);
    int rbase = (Lq >> 4)*8;
    unsigned int w[4];
    #pragma unroll
    for (int p=0;p<4;p++){
      unsigned int lo = f2b(sh[(rbase + 2*p    )*32 + col]);
      unsigned int hi = f2b(sh[(rbase + 2*p + 1)*32 + col]);
      w[p] = lo | (hi << 16);
    }
    hfrag[(ks32*2 + nt)*64 + half*32 + Lq] = make_uint4(w[0],w[1],w[2],w[3]);
  }
}

// ---- ALL 10 layers fused, NORMAL launch, barrier v2 between layers (R7-verified).
// Body: R6-verified vcat-fused layer (neigh -> reduce -> fused gi/gh -> GRU);
// msg phase and smsg LDS eliminated; h carried in registers across layers.
__launch_bounds__(512)
__global__ void k_layers(const unsigned int* __restrict__ mask3,
                         unsigned int* __restrict__ hfrag0,
                         unsigned int* __restrict__ hfrag1,
                         const float* __restrict__ hf32,
                         const int* __restrict__ deg,
                         const unsigned short* __restrict__ cw,
                         const unsigned short* __restrict__ vcat,
                         const float* __restrict__ bwv,
                         const int* __restrict__ bidx,
                         float* __restrict__ seg, float* __restrict__ cnt,
                         unsigned short* __restrict__ out16, float* __restrict__ out32,
                         const int* __restrict__ flag, int* bar)
{
  __shared__ __align__(16) char uni[33792];                 // spart[8][32][33] f32 | sgi[32][100]+sgh[32][100]
  __shared__ __align__(16) unsigned short sA[32][72];       // [h(0..32)|neigh(32..64)|pad]
  __shared__ int sdeg[32];

  const int t = threadIdx.x;
  const int b = blockIdx.x;            // 32-row tile [0,256)
  const int w = t >> 6, L = t & 63;
  const int q = L >> 4, lc = L & 15;
  const int rowbase = b*32;

  // elementwise mapping: thread -> (row r, cols cl and cl+16)
  const int r0 = t >> 4;               // [0,32)
  const int cl = t & 15;
  const int r  = rowbase + r0;
  const int isb = flag[0];
  const int dgr = deg[r];
  const float invr = dgr > 0 ? 1.f/(float)dgr : 0.f;
  float h0 = hf32[r*32 + cl];
  float h1 = hf32[r*32 + 16 + cl];
  if (cl == 0) sdeg[r0] = dgr;

  for (int d = 0; d < 10; ++d){
    const unsigned short* vcd = vcat + (size_t)d*6144;      // [96][64]
    const float*          bwd = bwv + d*96;                 // [96]
    const unsigned short* whh = cw + 412160 + d*3072;
    const unsigned short* bih = cw + 442880 + d*96;
    const unsigned short* bhh = cw + 443840 + d*96;
    const uint4*  hfragIn  = (const uint4*)((d & 1) ? hfrag1 : hfrag0);
    unsigned int* hfragOut = (d & 1) ? hfrag0 : hfrag1;
    const int last = (d == 9);

    sA[r0][cl]    = f2b(h0);
    sA[r0][16+cl] = f2b(h1);

    // ---- neigh: wave w = K-chunk of 1024 cols; 2 row-tiles (rt) of 16 ----
    {
      f32x4 a00={0,0,0,0}, a01={0,0,0,0}, a10={0,0,0,0}, a11={0,0,0,0};
      const unsigned int* mp = mask3 + (size_t)b*8192 + w*512 + L;     // rt stride 4096
      const uint4* bp = hfragIn + (size_t)w*4096 + L;
      for (int g=0; g<8; g++){
        unsigned int mw0 = mp[g*64];
        unsigned int mw1 = mp[4096 + g*64];
        #pragma unroll
        for (int s=0; s<4; s++){
          int ks = g*4 + s;
          uint4 u0 = bp[ks*128];
          uint4 u1 = bp[ks*128 + 64];
          union { unsigned int u[4]; bf16x8 v; } A0, A1, B0, B1;
          spread8((mw0 >> (8*s)) & 0xFFu, A0.u);
          spread8((mw1 >> (8*s)) & 0xFFu, A1.u);
          B0.u[0]=u0.x; B0.u[1]=u0.y; B0.u[2]=u0.z; B0.u[3]=u0.w;
          B1.u[0]=u1.x; B1.u[1]=u1.y; B1.u[2]=u1.z; B1.u[3]=u1.w;
          a00 = __builtin_amdgcn_mfma_f32_16x16x32_bf16(A0.v, B0.v, a00, 0,0,0);
          a01 = __builtin_amdgcn_mfma_f32_16x16x32_bf16(A0.v, B1.v, a01, 0,0,0);
          a10 = __builtin_amdgcn_mfma_f32_16x16x32_bf16(A1.v, B0.v, a10, 0,0,0);
          a11 = __builtin_amdgcn_mfma_f32_16x16x32_bf16(A1.v, B1.v, a11, 0,0,0);
        }
      }
      float* sp = (float*)uni + w*1056;                      // [32][33]
      #pragma unroll
      for (int rg=0; rg<4; rg++){
        int rw = q*4 + rg;
        sp[rw*33 + lc]         = a00[rg];
        sp[rw*33 + 16 + lc]    = a01[rg];
        sp[(16+rw)*33 + lc]    = a10[rg];
        sp[(16+rw)*33 + 16+lc] = a11[rg];
      }
    }
    __syncthreads();
    // ---- reduce 8 K-chunks -> sA neigh half ----
    {
      const float* spf = (const float*)uni;
      float s0 = 0.f, s1 = 0.f;
      #pragma unroll
      for (int ww=0; ww<8; ww++){
        s0 += spf[ww*1056 + r0*33 + cl];
        s1 += spf[ww*1056 + r0*33 + 16 + cl];
      }
      sA[r0][32+cl] = f2b(s0*invr);
      sA[r0][48+cl] = f2b(s1*invr);
    }
    __syncthreads();
    // ---- fused gi (waves 0-5, K=64 over [h|neigh] vs Vcat) / gh (waves 6-7) ----
    {
      float* sgi = (float*)uni;                               // [32][100]
      float* sgh = (float*)(uni + 12800);                     // [32][100]
      if (w < 6){
        int nt = w;
        union { uint4 u; bf16x8 v; } B0, B1;
        B0.u = *(const uint4*)(vcd + (size_t)(nt*16 + lc)*64 + q*8);
        B1.u = *(const uint4*)(vcd + (size_t)(nt*16 + lc)*64 + 32 + q*8);
        float bw = bwd[nt*16 + lc];
        #pragma unroll
        for (int rt=0; rt<2; rt++){
          union { uint4 u; bf16x8 v; } A0, A1;
          A0.u = *(const uint4*)&sA[rt*16 + lc][q*8];         // h part (K 0..31)
          A1.u = *(const uint4*)&sA[rt*16 + lc][32 + q*8];    // neigh part (K 32..63)
          f32x4 g0 = {0,0,0,0};
          g0 = __builtin_amdgcn_mfma_f32_16x16x32_bf16(A0.v, B0.v, g0, 0,0,0);
          g0 = __builtin_amdgcn_mfma_f32_16x16x32_bf16(A1.v, B1.v, g0, 0,0,0);
          #pragma unroll
          for (int rg=0; rg<4; rg++){
            int rw = rt*16 + q*4 + rg;
            float v = g0[rg] + bw;
            if (sdeg[rw] == 0) v = 0.f;
            sgi[rw*100 + nt*16 + lc] = v;
          }
        }
      } else {
        int rt = w - 6;
        union { uint4 u; bf16x8 v; } A;
        A.u = *(const uint4*)&sA[rt*16 + lc][q*8];
        #pragma unroll
        for (int nt=0; nt<6; nt++){
          union { uint4 u; bf16x8 v; } B;
          B.u = *(const uint4*)(whh + (size_t)(nt*16 + lc)*32 + q*8);
          f32x4 hh = {0,0,0,0};
          hh = __builtin_amdgcn_mfma_f32_16x16x32_bf16(A.v, B.v, hh, 0,0,0);
          #pragma unroll
          for (int rg=0; rg<4; rg++)
            sgh[(rt*16 + q*4+rg)*100 + nt*16 + lc] = hh[rg];
        }
      }
    }
    __syncthreads();
    // ---- GRU elementwise + hfragOut write (r4-verified pairing) ----
    {
      const float* sgi = (const float*)uni;
      const float* sgh = (const float*)(uni + 12800);
      float ir0 = sgi[r0*100 + cl]    + b2f(bih[cl]),    hr0 = sgh[r0*100 + cl]    + b2f(bhh[cl]);
      float iz0 = sgi[r0*100 + 32+cl] + b2f(bih[32+cl]), hz0 = sgh[r0*100 + 32+cl] + b2f(bhh[32+cl]);
      float in0 = sgi[r0*100 + 64+cl] + b2f(bih[64+cl]), hn0 = sgh[r0*100 + 64+cl] + b2f(bhh[64+cl]);
      float ir1 = sgi[r0*100 + 16+cl] + b2f(bih[16+cl]), hr1 = sgh[r0*100 + 16+cl] + b2f(bhh[16+cl]);
      float iz1 = sgi[r0*100 + 48+cl] + b2f(bih[48+cl]), hz1 = sgh[r0*100 + 48+cl] + b2f(bhh[48+cl]);
      float in1 = sgi[r0*100 + 80+cl] + b2f(bih[80+cl]), hn1 = sgh[r0*100 + 80+cl] + b2f(bhh[80+cl]);
      float rr0 = fsig(ir0 + hr0), zz0 = fsig(iz0 + hz0);
      float rr1 = fsig(ir1 + hr1), zz1 = fsig(iz1 + hz1);
      float nn0 = ftanh(in0 + rr0*hn0);
      float nn1 = ftanh(in1 + rr1*hn1);
      h0 = (1.f - zz0)*nn0 + zz0*h0;
      h1 = (1.f - zz1)*nn1 + zz1*h1;
      unsigned int m0 = f2b(h0), m1 = f2b(h1);
      if (!last){
        unsigned int p0 = (unsigned int)__shfl_xor((int)m0, 16);
        unsigned int p1 = (unsigned int)__shfl_xor((int)m1, 16);
        if ((r & 1) == 0){
          int ks32 = r >> 5;
          int Lf = ((r >> 3) & 3)*16 + cl;
          int pidx = (r & 7) >> 1;
          hfragOut[((ks32*2 + 0)*64 + Lf)*4 + pidx] = m0 | (p0 << 16);
          hfragOut[((ks32*2 + 1)*64 + Lf)*4 + pidx] = m1 | (p1 << 16);
        }
      } else {
        if (isb){ out16[r*32 + cl] = (unsigned short)m0; out16[r*32 + 16 + cl] = (unsigned short)m1; }
        else    { out32[r*32 + cl] = h0; out32[r*32 + 16 + cl] = h1; }
        int gb = bidx[r];
        atomicAdd(seg + gb*32 + cl, h0);
        atomicAdd(seg + gb*32 + 16 + cl, h1);
        if (cl == 0) atomicAdd(cnt + gb, 1.f);
      }
    }
    if (!last) gbar(bar);
  }
}

__global__ void k_pool(const float* __restrict__ seg, const float* __restrict__ cnt,
                       const unsigned short* __restrict__ pw, const unsigned short* __restrict__ pb,
                       const int* __restrict__ flag,
                       unsigned short* __restrict__ outG16, float* __restrict__ outG32){
  int g = blockIdx.x, o = threadIdx.x;
  float cv = cnt[g];
  float ic = cv > 0.f ? 1.f/cv : 0.f;
  float s = 0.f;
  #pragma unroll
  for (int c=0;c<32;c++) s += seg[g*32+c]*ic*b2f(pw[o*32+c]);
  s += b2f(pb[o]);
  if (flag[0]) outG16[g*256 + o] = f2b(s);
  else         outG32[g*256 + o] = s;
}

extern "C" void kernel_launch(void* const* d_in, const int* in_sizes, int n_in,
                              void* d_out, int out_size, void* d_ws, size_t ws_size,
                              hipStream_t stream){
  const int* af   = (const int*)d_in[0];
  const int* bft  = (const int*)d_in[1];
  const int* adj  = (const int*)d_in[2];
  const int* bidx = (const int*)d_in[3];

  char* ws = (char*)d_ws;                                    // ~11.6 MB total
  unsigned int*   mask3  = (unsigned int*)(ws + 0);          // 8 MB
  unsigned int*   hfrag0 = (unsigned int*)(ws + 8388608);    // 512 KB
  unsigned int*   hfrag1 = (unsigned int*)(ws + 8912896);    // 512 KB
  float*          hf32   = (float*)(ws + 9437184);           // 1 MB
  int*            deg    = (int*)(ws + 10485760);            // 32 KB
  float*          seg    = (float*)(ws + 10518528);          // 32 KB
  float*          cnt    = (float*)(ws + 10551296);          // 1 KB
  int*            flag   = (int*)(ws + 10552320);            // 64 B (flag[0]=dtype, flag[4..5]=gbar)
  unsigned short* cw     = (unsigned short*)(ws + 10552384); // 906 KB canonical bf16 weights
  unsigned short* vcat   = (unsigned short*)(ws + 11458880); // 120 KB fused Vcat (10 x 96x64)
  float*          bwv    = (float*)(ws + 11581760);          // 3.75 KB fused bias b@wih^T

  unsigned short* o16 = (unsigned short*)d_out;
  float*          o32 = (float*)d_out;
  int*            bar = flag + 4;

  k_prep<<<1803, 256, 0, stream>>>(d_in[6], d_in[7], d_in[8], d_in[9], d_in[10],
                                   d_in[11], d_in[12], d_in[13],
                                   (const unsigned short*)d_in[4],
                                   cw, deg, seg, cnt, flag);
  k_fuse<<<40, 256, 0, stream>>>(cw, vcat, bwv);
  k_pack<<<8192, 256, 0, stream>>>(adj, mask3, deg);
  k_be<<<2560, 512, 0, stream>>>(af, d_in[4], bft, d_in[5], flag,
                                 hf32, (uint4*)hfrag0,
                                 o16 + 262144, o32 + 262144);

  k_layers<<<256, 512, 0, stream>>>(mask3, hfrag0, hfrag1, hf32, deg, cw,
                                    vcat, bwv, bidx, seg, cnt, o16, o32, flag, bar);

  k_pool<<<256, 256, 0, stream>>>(seg, cnt, cw + 444800, cw + 452992, flag,
                                  o16 + 1310720, o32 + 1310720);
}

// Round 9
// 543.638 us; speedup vs baseline: 1.1785x; 1.1785x over previous
//
#include <hip/hip_runtime.h>
#include <stdint.h>

typedef __bf16 bf16x8 __attribute__((ext_vector_type(8)));
typedef float f32x4 __attribute__((ext_vector_type(4)));

__device__ __forceinline__ float b2f(unsigned short u){
  unsigned int t = ((unsigned int)u) << 16;
  return __builtin_bit_cast(float, t);
}
__device__ __forceinline__ unsigned short f2b(float f){
  unsigned int x = __builtin_bit_cast(unsigned int, f);
  x = x + 0x7FFFu + ((x >> 16) & 1u);
  return (unsigned short)(x >> 16);
}
// spread 8 bits -> 8 packed bf16 {0.0,1.0} (element j = bit j)
__device__ __forceinline__ void spread8(unsigned int B, unsigned int w[4]){
  unsigned int m = __umul24(B, 0x8001u);
  w[0] = __umul24(m & 0x00010001u, 0x3F80u);
  w[1] = __umul24(m & 0x00040004u, 0x0FE0u);
  w[2] = __umul24(m & 0x00100010u, 0x03F8u);
  w[3] = __umul24(m & 0x00400040u, 0x00FEu);
}
__device__ __forceinline__ float fsig(float x){ return 1.f/(1.f + __expf(-x)); }
__device__ __forceinline__ float ftanh(float x){ return 1.f - 2.f/(__expf(2.f*x) + 1.f); }

// ---- merged setup: weights convert + zero + atom-embed + bond-embed ----
// blocks [0,886): weight convert; 886: zero seg/cnt + flag; [887,1399): embed;
// [1399,3447): bond gather. Each block computes the dtype vote locally (no
// cross-block flag dependency inside this dispatch).
__global__ void k_setup(const void* s_msgW, const void* s_msgb, const void* s_wih,
                        const void* s_whh, const void* s_bih, const void* s_bhh,
                        const void* s_poolW, const void* s_poolb,
                        const unsigned short* __restrict__ aemb_u16,
                        const int* __restrict__ af, const void* __restrict__ araw,
                        const int* __restrict__ bft, const void* __restrict__ braw,
                        unsigned short* __restrict__ cw,
                        float* __restrict__ seg, float* __restrict__ cnt,
                        int* __restrict__ flag,
                        float* __restrict__ hf32, uint4* __restrict__ hfrag,
                        unsigned short* __restrict__ outB16, float* __restrict__ outB32){
  int b = blockIdx.x, t = threadIdx.x;
  unsigned int uu = aemb_u16[2*t];
  int e = (int)((uu >> 7) & 0xFF);
  unsigned long long vote = __ballot(e >= 100 && e <= 127);
  int isb = (__popcll(vote) > 32) ? 1 : 0;

  if (b < 886){
    int id = b*512 + t;
    if (id < 453248){
      const void* src; int off;
      if      (id < 163840){ src = s_msgW;  off = id; }
      else if (id < 166400){ src = s_msgb;  off = id - 163840; }
      else if (id < 412160){ src = s_wih;   off = id - 166400; }
      else if (id < 442880){ src = s_whh;   off = id - 412160; }
      else if (id < 443840){ src = s_bih;   off = id - 442880; }
      else if (id < 444800){ src = s_bhh;   off = id - 443840; }
      else if (id < 452992){ src = s_poolW; off = id - 444800; }
      else                 { src = s_poolb; off = id - 452992; }
      cw[id] = isb ? ((const unsigned short*)src)[off]
                   : f2b(((const float*)src)[off]);
    }
    return;
  }
  if (b == 886){
    #pragma unroll
    for (int i=0;i<16;i++){ int j = i*512 + t; seg[j] = 0.f; }
    if (t < 256) cnt[t] = 0.f;
    if (t == 0) flag[0] = isb;
    return;
  }
  if (b < 1399){
    // ---- atom embed: hf32 + hfrag0 (B-operand layout), r3-verified algebra ----
    __shared__ __align__(16) float sh[512];
    int eb = b - 887;
    int r = t >> 5, c = t & 31;
    int row = eb*16 + r;
    int idx = af[row]*32 + c;
    float f;
    if (isb) f = b2f(((const unsigned short*)araw)[idx]);
    else     f = ((const float*)araw)[idx];
    hf32[row*32 + c] = f;
    sh[r*32 + c] = f;
    __syncthreads();
    if (t < 64){
      int nt = t >> 5, Lq = t & 31;
      int ks32 = eb >> 1, half = eb & 1;
      int col = nt*16 + (Lq & 15);
      int rbase = (Lq >> 4)*8;
      unsigned int w[4];
      #pragma unroll
      for (int p=0;p<4;p++){
        unsigned int lo = f2b(sh[(rbase + 2*p    )*32 + col]);
        unsigned int hi = f2b(sh[(rbase + 2*p + 1)*32 + col]);
        w[p] = lo | (hi << 16);
      }
      hfrag[(ks32*2 + nt)*64 + half*32 + Lq] = make_uint4(w[0],w[1],w[2],w[3]);
    }
    return;
  }
  // ---- bond gather ----
  {
    int id = (b - 1399)*512 + t;           // [0, 1048576)
    int e2 = id >> 5, c = id & 31;
    int idx = bft[e2]*32 + c;
    if (isb) outB16[id] = ((const unsigned short*)braw)[idx];
    else     outB32[id] = ((const float*)braw)[idx];
  }
}

// ---- one full layer per kernel: neigh (8-way K-split) -> reduce -> msg -> gi/gh -> GRU.
// FIRST=1 (layer 0): packs its own 32 adjacency rows into LDS masks + computes deg
// locally (perfect block locality: mask3 slice b*8192.. is exactly rows 32b..32b+31),
// writes mask3/deg for later layers, runs neigh off LDS.
template<int FIRST>
__launch_bounds__(512, 1)
__global__ void k_layer(const int* __restrict__ adj,
                        unsigned int* __restrict__ mask3,
                        const uint4* __restrict__ hfragIn,
                        unsigned int* __restrict__ hfragOut,
                        float* __restrict__ hf32,
                        int* __restrict__ deg,
                        const unsigned short* __restrict__ msgW,
                        const unsigned short* __restrict__ msgb,
                        const unsigned short* __restrict__ wih,
                        const unsigned short* __restrict__ whh,
                        const unsigned short* __restrict__ bih,
                        const unsigned short* __restrict__ bhh,
                        const int* __restrict__ bidx,
                        float* __restrict__ seg, float* __restrict__ cnt,
                        unsigned short* __restrict__ out16, float* __restrict__ out32,
                        const int* __restrict__ flag, int last)
{
  __shared__ __align__(16) char uni[33792];                 // spart[8][32][33] f32 | sgi[32][100]+sgh[32][100]
  __shared__ __align__(16) unsigned short sA[32][72];       // [h(0..32)|neigh(32..64)|pad]
  __shared__ __align__(16) unsigned short smsg[32][264];
  __shared__ __align__(16) unsigned int smask[FIRST ? 8192 : 64];
  __shared__ int sdeg[32];

  const int t = threadIdx.x;
  const int b = blockIdx.x;            // 32-row tile [0,256)
  const int w = t >> 6, L = t & 63;
  const int q = L >> 4, lc = L & 15;
  const int rowbase = b*32;

  // elementwise mapping: thread -> (row r, cols cl and cl+16)
  const int r0 = t >> 4;               // [0,32)
  const int cl = t & 15;
  const int r  = rowbase + r0;
  const int isb = flag[0];
  float h0 = hf32[r*32 + cl];
  float h1 = hf32[r*32 + 16 + cl];
  sA[r0][cl]    = f2b(h0);
  sA[r0][16+cl] = f2b(h1);

  if (FIRST){
    // ---- in-kernel adjacency pack for this block's 32 rows (r3-verified mapping) ----
    if (t < 32) sdeg[t] = 0;
    __syncthreads();
    #pragma unroll
    for (int i=0;i<16;i++){
      int l = i*512 + t;                 // [0,8192)
      int rbl = l >> 12;
      int rem = l & 4095;
      int kgg = rem >> 6;
      int L2  = rem & 63;
      int lc2 = L2 & 15, q2 = L2 >> 4;
      int row = rowbase + rbl*16 + lc2;
      const int4* p4 = (const int4*)(adj + (size_t)row*8192 + kgg*128 + q2*8);
      unsigned int dw = 0; int pc = 0;
      #pragma unroll
      for (int s2=0;s2<4;s2++){
        int4 u = p4[s2*8];
        int4 v = p4[s2*8 + 1];
        unsigned int bb = (unsigned int)(u.x > 0)
                        | ((unsigned int)(u.y > 0) << 1)
                        | ((unsigned int)(u.z > 0) << 2)
                        | ((unsigned int)(u.w > 0) << 3)
                        | ((unsigned int)(v.x > 0) << 4)
                        | ((unsigned int)(v.y > 0) << 5)
                        | ((unsigned int)(v.z > 0) << 6)
                        | ((unsigned int)(v.w > 0) << 7);
        dw |= bb << (8*s2);
        pc += __popc(bb);
      }
      smask[l] = dw;
      mask3[(size_t)b*8192 + l] = dw;    // for layers 1..9
      pc += __shfl_xor(pc, 16);
      pc += __shfl_xor(pc, 32);
      if (q2 == 0) atomicAdd(&sdeg[rbl*16 + lc2], pc);
    }
    __syncthreads();
    if (t < 32) deg[rowbase + t] = sdeg[t];   // for layers 1..9
  }

  const int dgr = FIRST ? sdeg[r0] : deg[r];
  if (!FIRST && cl == 0) sdeg[r0] = dgr;
  const float invr = dgr > 0 ? 1.f/(float)dgr : 0.f;

  // ---- neigh: wave w = K-chunk of 1024 cols; 2 row-tiles (rt) of 16 ----
  {
    f32x4 a00={0,0,0,0}, a01={0,0,0,0}, a10={0,0,0,0}, a11={0,0,0,0};
    const uint4* bp = hfragIn + (size_t)w*4096 + L;
    if (FIRST){
      const unsigned int* mp = smask + w*512 + L;
      for (int g=0; g<8; g++){
        unsigned int mw0 = mp[g*64];
        unsigned int mw1 = mp[4096 + g*64];
        #pragma unroll
        for (int s=0; s<4; s++){
          int ks = g*4 + s;
          uint4 u0 = bp[ks*128];
          uint4 u1 = bp[ks*128 + 64];
          union { unsigned int u[4]; bf16x8 v; } A0, A1, B0, B1;
          spread8((mw0 >> (8*s)) & 0xFFu, A0.u);
          spread8((mw1 >> (8*s)) & 0xFFu, A1.u);
          B0.u[0]=u0.x; B0.u[1]=u0.y; B0.u[2]=u0.z; B0.u[3]=u0.w;
          B1.u[0]=u1.x; B1.u[1]=u1.y; B1.u[2]=u1.z; B1.u[3]=u1.w;
          a00 = __builtin_amdgcn_mfma_f32_16x16x32_bf16(A0.v, B0.v, a00, 0,0,0);
          a01 = __builtin_amdgcn_mfma_f32_16x16x32_bf16(A0.v, B1.v, a01, 0,0,0);
          a10 = __builtin_amdgcn_mfma_f32_16x16x32_bf16(A1.v, B0.v, a10, 0,0,0);
          a11 = __builtin_amdgcn_mfma_f32_16x16x32_bf16(A1.v, B1.v, a11, 0,0,0);
        }
      }
    } else {
      const unsigned int* mp = mask3 + (size_t)b*8192 + w*512 + L;   // rt stride 4096
      for (int g=0; g<8; g++){
        unsigned int mw0 = mp[g*64];
        unsigned int mw1 = mp[4096 + g*64];
        #pragma unroll
        for (int s=0; s<4; s++){
          int ks = g*4 + s;
          uint4 u0 = bp[ks*128];
          uint4 u1 = bp[ks*128 + 64];
          union { unsigned int u[4]; bf16x8 v; } A0, A1, B0, B1;
          spread8((mw0 >> (8*s)) & 0xFFu, A0.u);
          spread8((mw1 >> (8*s)) & 0xFFu, A1.u);
          B0.u[0]=u0.x; B0.u[1]=u0.y; B0.u[2]=u0.z; B0.u[3]=u0.w;
          B1.u[0]=u1.x; B1.u[1]=u1.y; B1.u[2]=u1.z; B1.u[3]=u1.w;
          a00 = __builtin_amdgcn_mfma_f32_16x16x32_bf16(A0.v, B0.v, a00, 0,0,0);
          a01 = __builtin_amdgcn_mfma_f32_16x16x32_bf16(A0.v, B1.v, a01, 0,0,0);
          a10 = __builtin_amdgcn_mfma_f32_16x16x32_bf16(A1.v, B0.v, a10, 0,0,0);
          a11 = __builtin_amdgcn_mfma_f32_16x16x32_bf16(A1.v, B1.v, a11, 0,0,0);
        }
      }
    }
    float* sp = (float*)uni + w*1056;                      // [32][33]
    #pragma unroll
    for (int rg=0; rg<4; rg++){
      int rw = q*4 + rg;
      sp[rw*33 + lc]         = a00[rg];
      sp[rw*33 + 16 + lc]    = a01[rg];
      sp[(16+rw)*33 + lc]    = a10[rg];
      sp[(16+rw)*33 + 16+lc] = a11[rg];
    }
  }
  __syncthreads();
  // ---- reduce 8 K-chunks -> sA neigh half ----
  {
    const float* spf = (const float*)uni;
    float s0 = 0.f, s1 = 0.f;
    #pragma unroll
    for (int ww=0; ww<8; ww++){
      s0 += spf[ww*1056 + r0*33 + cl];
      s1 += spf[ww*1056 + r0*33 + 16 + cl];
    }
    sA[r0][32+cl] = f2b(s0*invr);
    sA[r0][48+cl] = f2b(s1*invr);
  }
  __syncthreads();
  // ---- msg GEMM: wave w -> rt=w&1, nt = (w>>1)*4 .. +3 ----
  {
    int rt = w & 1, ntb = (w >> 1)*4;
    union { uint4 u; bf16x8 v; } A0, A1;
    A0.u = *(const uint4*)&sA[rt*16 + lc][q*8];
    A1.u = *(const uint4*)&sA[rt*16 + lc][32 + q*8];
    #pragma unroll
    for (int i=0; i<4; i++){
      int nt = ntb + i;
      union { uint4 u; bf16x8 v; } B0, B1;
      B0.u = *(const uint4*)(msgW + (size_t)(nt*16 + lc)*64 + q*8);
      B1.u = *(const uint4*)(msgW + (size_t)(nt*16 + lc)*64 + 32 + q*8);
      f32x4 am = {0,0,0,0};
      am = __builtin_amdgcn_mfma_f32_16x16x32_bf16(A0.v, B0.v, am, 0,0,0);
      am = __builtin_amdgcn_mfma_f32_16x16x32_bf16(A1.v, B1.v, am, 0,0,0);
      float bv = b2f(msgb[nt*16 + lc]);
      #pragma unroll
      for (int rg=0; rg<4; rg++){
        int rw = rt*16 + q*4 + rg;
        float v = am[rg] + bv;
        if (sdeg[rw] == 0) v = 0.f;
        smsg[rw][nt*16 + lc] = f2b(v);
      }
    }
  }
  __syncthreads();
  // ---- gi (waves 0-5: nt=w, both rt) / gh (waves 6-7: rt=w-6, nt 0..5) ----
  {
    float* sgi = (float*)uni;                               // [32][100]
    float* sgh = (float*)(uni + 12800);                     // [32][100]
    if (w < 6){
      int nt = w;
      f32x4 g0 = {0,0,0,0}, g1 = {0,0,0,0};
      #pragma unroll
      for (int ks=0; ks<8; ks++){
        union { uint4 u; bf16x8 v; } A0, A1, B;
        B.u  = *(const uint4*)(wih + (size_t)(nt*16 + lc)*256 + ks*32 + q*8);
        A0.u = *(const uint4*)&smsg[lc][ks*32 + q*8];
        A1.u = *(const uint4*)&smsg[16 + lc][ks*32 + q*8];
        g0 = __builtin_amdgcn_mfma_f32_16x16x32_bf16(A0.v, B.v, g0, 0,0,0);
        g1 = __builtin_amdgcn_mfma_f32_16x16x32_bf16(A1.v, B.v, g1, 0,0,0);
      }
      #pragma unroll
      for (int rg=0; rg<4; rg++){
        sgi[(q*4+rg)*100      + nt*16 + lc] = g0[rg];
        sgi[(16+q*4+rg)*100   + nt*16 + lc] = g1[rg];
      }
    } else {
      int rt = w - 6;
      union { uint4 u; bf16x8 v; } A;
      A.u = *(const uint4*)&sA[rt*16 + lc][q*8];
      #pragma unroll
      for (int nt=0; nt<6; nt++){
        union { uint4 u; bf16x8 v; } B;
        B.u = *(const uint4*)(whh + (size_t)(nt*16 + lc)*32 + q*8);
        f32x4 hh = {0,0,0,0};
        hh = __builtin_amdgcn_mfma_f32_16x16x32_bf16(A.v, B.v, hh, 0,0,0);
        #pragma unroll
        for (int rg=0; rg<4; rg++)
          sgh[(rt*16 + q*4+rg)*100 + nt*16 + lc] = hh[rg];
      }
    }
  }
  __syncthreads();
  // ---- GRU elementwise + hfragOut write (r4-verified pairing) ----
  {
    const float* sgi = (const float*)uni;
    const float* sgh = (const float*)(uni + 12800);
    float ir0 = sgi[r0*100 + cl]    + b2f(bih[cl]),    hr0 = sgh[r0*100 + cl]    + b2f(bhh[cl]);
    float iz0 = sgi[r0*100 + 32+cl] + b2f(bih[32+cl]), hz0 = sgh[r0*100 + 32+cl] + b2f(bhh[32+cl]);
    float in0 = sgi[r0*100 + 64+cl] + b2f(bih[64+cl]), hn0 = sgh[r0*100 + 64+cl] + b2f(bhh[64+cl]);
    float ir1 = sgi[r0*100 + 16+cl] + b2f(bih[16+cl]), hr1 = sgh[r0*100 + 16+cl] + b2f(bhh[16+cl]);
    float iz1 = sgi[r0*100 + 48+cl] + b2f(bih[48+cl]), hz1 = sgh[r0*100 + 48+cl] + b2f(bhh[48+cl]);
    float in1 = sgi[r0*100 + 80+cl] + b2f(bih[80+cl]), hn1 = sgh[r0*100 + 80+cl] + b2f(bhh[80+cl]);
    float rr0 = fsig(ir0 + hr0), zz0 = fsig(iz0 + hz0);
    float rr1 = fsig(ir1 + hr1), zz1 = fsig(iz1 + hz1);
    float nn0 = ftanh(in0 + rr0*hn0);
    float nn1 = ftanh(in1 + rr1*hn1);
    h0 = (1.f - zz0)*nn0 + zz0*h0;
    h1 = (1.f - zz1)*nn1 + zz1*h1;
    hf32[r*32 + cl]      = h0;
    hf32[r*32 + 16 + cl] = h1;
    unsigned int m0 = f2b(h0), m1 = f2b(h1);
    if (!last){
      unsigned int p0 = (unsigned int)__shfl_xor((int)m0, 16);
      unsigned int p1 = (unsigned int)__shfl_xor((int)m1, 16);
      if ((r & 1) == 0){
        int ks32 = r >> 5;
        int Lf = ((r >> 3) & 3)*16 + cl;
        int pidx = (r & 7) >> 1;
        hfragOut[((ks32*2 + 0)*64 + Lf)*4 + pidx] = m0 | (p0 << 16);
        hfragOut[((ks32*2 + 1)*64 + Lf)*4 + pidx] = m1 | (p1 << 16);
      }
    } else {
      if (isb){ out16[r*32 + cl] = (unsigned short)m0; out16[r*32 + 16 + cl] = (unsigned short)m1; }
      else    { out32[r*32 + cl] = h0; out32[r*32 + 16 + cl] = h1; }
      int gb = bidx[r];
      atomicAdd(seg + gb*32 + cl, h0);
      atomicAdd(seg + gb*32 + 16 + cl, h1);
      if (cl == 0) atomicAdd(cnt + gb, 1.f);
    }
  }
}

__global__ void k_pool(const float* __restrict__ seg, const float* __restrict__ cnt,
                       const unsigned short* __restrict__ pw, const unsigned short* __restrict__ pb,
                       const int* __restrict__ flag,
                       unsigned short* __restrict__ outG16, float* __restrict__ outG32){
  int g = blockIdx.x, o = threadIdx.x;
  float cv = cnt[g];
  float ic = cv > 0.f ? 1.f/cv : 0.f;
  float s = 0.f;
  #pragma unroll
  for (int c=0;c<32;c++) s += seg[g*32+c]*ic*b2f(pw[o*32+c]);
  s += b2f(pb[o]);
  if (flag[0]) outG16[g*256 + o] = f2b(s);
  else         outG32[g*256 + o] = s;
}

extern "C" void kernel_launch(void* const* d_in, const int* in_sizes, int n_in,
                              void* d_out, int out_size, void* d_ws, size_t ws_size,
                              hipStream_t stream){
  const int* af   = (const int*)d_in[0];
  const int* bft  = (const int*)d_in[1];
  const int* adj  = (const int*)d_in[2];
  const int* bidx = (const int*)d_in[3];

  char* ws = (char*)d_ws;                                    // ~11.5 MB total
  unsigned int*   mask3  = (unsigned int*)(ws + 0);          // 8 MB
  unsigned int*   hfrag0 = (unsigned int*)(ws + 8388608);    // 512 KB
  unsigned int*   hfrag1 = (unsigned int*)(ws + 8912896);    // 512 KB
  float*          hf32   = (float*)(ws + 9437184);           // 1 MB
  int*            deg    = (int*)(ws + 10485760);            // 32 KB
  float*          seg    = (float*)(ws + 10518528);          // 32 KB
  float*          cnt    = (float*)(ws + 10551296);          // 1 KB
  int*            flag   = (int*)(ws + 10552320);            // 64 B
  unsigned short* cw     = (unsigned short*)(ws + 10552384); // 906 KB canonical bf16 weights

  unsigned short* o16 = (unsigned short*)d_out;
  float*          o32 = (float*)d_out;

  k_setup<<<3447, 512, 0, stream>>>(d_in[6], d_in[7], d_in[8], d_in[9], d_in[10],
                                    d_in[11], d_in[12], d_in[13],
                                    (const unsigned short*)d_in[4],
                                    af, d_in[4], bft, d_in[5],
                                    cw, seg, cnt, flag, hf32, (uint4*)hfrag0,
                                    o16 + 262144, o32 + 262144);

  for (int d = 0; d < 10; d++){
    const uint4*  hin  = (const uint4*)((d & 1) ? hfrag1 : hfrag0);
    unsigned int* hout = (d & 1) ? hfrag0 : hfrag1;
    if (d == 0)
      k_layer<1><<<256, 512, 0, stream>>>(adj, mask3, hin, hout, hf32, deg,
                                          cw + (size_t)d*16384,        cw + 163840 + d*256,
                                          cw + 166400 + (size_t)d*24576, cw + 412160 + d*3072,
                                          cw + 442880 + d*96,          cw + 443840 + d*96,
                                          bidx, seg, cnt, o16, o32, flag, 0);
    else
      k_layer<0><<<256, 512, 0, stream>>>(adj, mask3, hin, hout, hf32, deg,
                                          cw + (size_t)d*16384,        cw + 163840 + d*256,
                                          cw + 166400 + (size_t)d*24576, cw + 412160 + d*3072,
                                          cw + 442880 + d*96,          cw + 443840 + d*96,
                                          bidx, seg, cnt, o16, o32, flag, (d == 9) ? 1 : 0);
  }
  k_pool<<<256, 256, 0, stream>>>(seg, cnt, cw + 444800, cw + 452992, flag,
                                  o16 + 1310720, o32 + 1310720);
}

// Round 10
// 535.742 us; speedup vs baseline: 1.1959x; 1.0147x over previous
//
#include <hip/hip_runtime.h>
#include <stdint.h>

typedef __bf16 bf16x8 __attribute__((ext_vector_type(8)));
typedef float f32x4 __attribute__((ext_vector_type(4)));

__device__ __forceinline__ float b2f(unsigned short u){
  unsigned int t = ((unsigned int)u) << 16;
  return __builtin_bit_cast(float, t);
}
__device__ __forceinline__ unsigned short f2b(float f){
  unsigned int x = __builtin_bit_cast(unsigned int, f);
  x = x + 0x7FFFu + ((x >> 16) & 1u);
  return (unsigned short)(x >> 16);
}
// spread 8 bits -> 8 packed bf16 {0.0,1.0} (element j = bit j)
__device__ __forceinline__ void spread8(unsigned int B, unsigned int w[4]){
  unsigned int m = __umul24(B, 0x8001u);
  w[0] = __umul24(m & 0x00010001u, 0x3F80u);
  w[1] = __umul24(m & 0x00040004u, 0x0FE0u);
  w[2] = __umul24(m & 0x00100010u, 0x03F8u);
  w[3] = __umul24(m & 0x00400040u, 0x00FEu);
}
__device__ __forceinline__ float fsig(float x){ return 1.f/(1.f + __expf(-x)); }
__device__ __forceinline__ float ftanh(float x){ return 1.f - 2.f/(__expf(2.f*x) + 1.f); }

// ---- prep: dtype-vote + convert all weights to canonical bf16 + zero deg/seg/cnt ----
__global__ void k_prep(const void* s_msgW, const void* s_msgb, const void* s_wih,
                       const void* s_whh, const void* s_bih, const void* s_bhh,
                       const void* s_poolW, const void* s_poolb,
                       const unsigned short* __restrict__ aemb_u16,
                       unsigned short* __restrict__ cw,
                       int* __restrict__ deg, float* __restrict__ seg,
                       float* __restrict__ cnt, int* __restrict__ flag){
  int b = blockIdx.x, t = threadIdx.x;
  unsigned int uu = aemb_u16[2*t];
  int e = (int)((uu >> 7) & 0xFF);
  unsigned long long vote = __ballot(e >= 100 && e <= 127);
  int isb = (__popcll(vote) > 32) ? 1 : 0;
  if (b < 1771){
    int id = b*256 + t;
    if (id < 453248){
      const void* src; int off;
      if      (id < 163840){ src = s_msgW;  off = id; }
      else if (id < 166400){ src = s_msgb;  off = id - 163840; }
      else if (id < 412160){ src = s_wih;   off = id - 166400; }
      else if (id < 442880){ src = s_whh;   off = id - 412160; }
      else if (id < 443840){ src = s_bih;   off = id - 442880; }
      else if (id < 444800){ src = s_bhh;   off = id - 443840; }
      else if (id < 452992){ src = s_poolW; off = id - 444800; }
      else                 { src = s_poolb; off = id - 452992; }
      cw[id] = isb ? ((const unsigned short*)src)[off]
                   : f2b(((const float*)src)[off]);
    }
  } else {
    int id2 = (b - 1771)*256 + t;
    if (id2 < 8192){ deg[id2] = 0; seg[id2] = 0.f; }
    if (id2 < 256) cnt[id2] = 0.f;
    if (b == 1771 && t == 0) flag[0] = isb;
  }
}

// ---- pack adjacency into 16x16x32-A-fragment bit layout + degrees (r3-verified) ----
// vectorized: 8 x int4 loads per thread
__global__ void k_pack(const int* __restrict__ adj, unsigned int* __restrict__ mask3,
                       int* __restrict__ deg){
  int tid = blockIdx.x*256 + threadIdx.x;    // 2,097,152
  int rb  = tid >> 12;
  int rem = tid & 4095;
  int kgg = rem >> 6;
  int L   = rem & 63;
  int lc = L & 15, q = L >> 4;
  int row = rb*16 + lc;
  const int4* p4 = (const int4*)(adj + (size_t)row*8192 + kgg*128 + q*8);
  unsigned int dw = 0; int pc = 0;
  #pragma unroll
  for (int s=0;s<4;s++){
    int4 u = p4[s*8];
    int4 v = p4[s*8 + 1];
    unsigned int b = (unsigned int)(u.x > 0)
                   | ((unsigned int)(u.y > 0) << 1)
                   | ((unsigned int)(u.z > 0) << 2)
                   | ((unsigned int)(u.w > 0) << 3)
                   | ((unsigned int)(v.x > 0) << 4)
                   | ((unsigned int)(v.y > 0) << 5)
                   | ((unsigned int)(v.z > 0) << 6)
                   | ((unsigned int)(v.w > 0) << 7);
    dw |= b << (8*s);
    pc += __popc(b);
  }
  mask3[tid] = dw;
  pc += __shfl_xor(pc, 16);
  pc += __shfl_xor(pc, 32);
  if (q == 0) atomicAdd(deg + row, pc);
}

// ---- merged bond-embedding + atom-embedding (saves one dispatch gap) ----
// blocks [0,512): embed (512 thr); blocks [512,2560): bond gather (512 thr)
__global__ void k_be(const int* __restrict__ af, const void* __restrict__ araw,
                     const int* __restrict__ bft, const void* __restrict__ braw,
                     const int* __restrict__ flag,
                     float* __restrict__ hf32, uint4* __restrict__ hfrag,
                     unsigned short* __restrict__ outB16, float* __restrict__ outB32){
  int b = blockIdx.x, t = threadIdx.x;
  if (b >= 512){
    int id = (b - 512)*512 + t;            // [0, 1048576)
    int e = id >> 5, c = id & 31;
    int idx = bft[e]*32 + c;
    if (flag[0]) outB16[id] = ((const unsigned short*)braw)[idx];
    else         outB32[id] = ((const float*)braw)[idx];
    return;
  }
  __shared__ __align__(16) float sh[512];
  int r = t >> 5, c = t & 31;
  int row = b*16 + r;
  int idx = af[row]*32 + c;
  float f;
  if (flag[0]) f = b2f(((const unsigned short*)araw)[idx]);
  else         f = ((const float*)araw)[idx];
  hf32[row*32 + c] = f;
  sh[r*32 + c] = f;
  __syncthreads();
  if (t < 64){
    int nt = t >> 5, Lq = t & 31;
    int ks32 = b >> 1, half = b & 1;
    int col = nt*16 + (Lq & 15);
    int rbase = (Lq >> 4)*8;
    unsigned int w[4];
    #pragma unroll
    for (int p=0;p<4;p++){
      unsigned int lo = f2b(sh[(rbase + 2*p    )*32 + col]);
      unsigned int hi = f2b(sh[(rbase + 2*p + 1)*32 + col]);
      w[p] = lo | (hi << 16);
    }
    hfrag[(ks32*2 + nt)*64 + half*32 + Lq] = make_uint4(w[0],w[1],w[2],w[3]);
  }
}

// ---- one full layer per kernel: neigh (8-way K-split) -> reduce -> msg -> gi/gh -> GRU ----
__launch_bounds__(512, 1)
__global__ void k_layer(const unsigned int* __restrict__ mask3,
                        const uint4* __restrict__ hfragIn,
                        unsigned int* __restrict__ hfragOut,
                        float* __restrict__ hf32,
                        const int* __restrict__ deg,
                        const unsigned short* __restrict__ msgW,
                        const unsigned short* __restrict__ msgb,
                        const unsigned short* __restrict__ wih,
                        const unsigned short* __restrict__ whh,
                        const unsigned short* __restrict__ bih,
                        const unsigned short* __restrict__ bhh,
                        const int* __restrict__ bidx,
                        float* __restrict__ seg, float* __restrict__ cnt,
                        unsigned short* __restrict__ out16, float* __restrict__ out32,
                        const int* __restrict__ flag, int last)
{
  __shared__ __align__(16) char uni[33792];                 // spart[8][32][33] f32 | sgi[32][100]+sgh[32][100]
  __shared__ __align__(16) unsigned short sA[32][72];       // [h(0..32)|neigh(32..64)|pad]
  __shared__ __align__(16) unsigned short smsg[32][264];
  __shared__ int sdeg[32];

  const int t = threadIdx.x;
  const int b = blockIdx.x;            // 32-row tile [0,256)
  const int w = t >> 6, L = t & 63;
  const int q = L >> 4, lc = L & 15;
  const int rowbase = b*32;

  // elementwise mapping: thread -> (row r, cols cl and cl+16)
  const int r0 = t >> 4;               // [0,32)
  const int cl = t & 15;
  const int r  = rowbase + r0;
  const int isb = flag[0];
  const int dgr = deg[r];
  const float invr = dgr > 0 ? 1.f/(float)dgr : 0.f;
  float h0 = hf32[r*32 + cl];
  float h1 = hf32[r*32 + 16 + cl];
  sA[r0][cl]    = f2b(h0);
  sA[r0][16+cl] = f2b(h1);
  if (cl == 0) sdeg[r0] = dgr;

  // ---- neigh: wave w = K-chunk of 1024 cols; 2 row-tiles (rt) of 16 ----
  {
    f32x4 a00={0,0,0,0}, a01={0,0,0,0}, a10={0,0,0,0}, a11={0,0,0,0};
    const unsigned int* mp = mask3 + (size_t)b*8192 + w*512 + L;     // rt stride 4096
    const uint4* bp = hfragIn + (size_t)w*4096 + L;
    for (int g=0; g<8; g++){
      unsigned int mw0 = mp[g*64];
      unsigned int mw1 = mp[4096 + g*64];
      #pragma unroll
      for (int s=0; s<4; s++){
        int ks = g*4 + s;
        uint4 u0 = bp[ks*128];
        uint4 u1 = bp[ks*128 + 64];
        union { unsigned int u[4]; bf16x8 v; } A0, A1, B0, B1;
        spread8((mw0 >> (8*s)) & 0xFFu, A0.u);
        spread8((mw1 >> (8*s)) & 0xFFu, A1.u);
        B0.u[0]=u0.x; B0.u[1]=u0.y; B0.u[2]=u0.z; B0.u[3]=u0.w;
        B1.u[0]=u1.x; B1.u[1]=u1.y; B1.u[2]=u1.z; B1.u[3]=u1.w;
        a00 = __builtin_amdgcn_mfma_f32_16x16x32_bf16(A0.v, B0.v, a00, 0,0,0);
        a01 = __builtin_amdgcn_mfma_f32_16x16x32_bf16(A0.v, B1.v, a01, 0,0,0);
        a10 = __builtin_amdgcn_mfma_f32_16x16x32_bf16(A1.v, B0.v, a10, 0,0,0);
        a11 = __builtin_amdgcn_mfma_f32_16x16x32_bf16(A1.v, B1.v, a11, 0,0,0);
      }
    }
    float* sp = (float*)uni + w*1056;                      // [32][33]
    #pragma unroll
    for (int rg=0; rg<4; rg++){
      int rw = q*4 + rg;
      sp[rw*33 + lc]         = a00[rg];
      sp[rw*33 + 16 + lc]    = a01[rg];
      sp[(16+rw)*33 + lc]    = a10[rg];
      sp[(16+rw)*33 + 16+lc] = a11[rg];
    }
  }
  __syncthreads();
  // ---- reduce 8 K-chunks -> sA neigh half ----
  {
    const float* spf = (const float*)uni;
    float s0 = 0.f, s1 = 0.f;
    #pragma unroll
    for (int ww=0; ww<8; ww++){
      s0 += spf[ww*1056 + r0*33 + cl];
      s1 += spf[ww*1056 + r0*33 + 16 + cl];
    }
    sA[r0][32+cl] = f2b(s0*invr);
    sA[r0][48+cl] = f2b(s1*invr);
  }
  __syncthreads();
  // ---- msg GEMM: wave w -> rt=w&1, nt = (w>>1)*4 .. +3 ----
  {
    int rt = w & 1, ntb = (w >> 1)*4;
    union { uint4 u; bf16x8 v; } A0, A1;
    A0.u = *(const uint4*)&sA[rt*16 + lc][q*8];
    A1.u = *(const uint4*)&sA[rt*16 + lc][32 + q*8];
    #pragma unroll
    for (int i=0; i<4; i++){
      int nt = ntb + i;
      union { uint4 u; bf16x8 v; } B0, B1;
      B0.u = *(const uint4*)(msgW + (size_t)(nt*16 + lc)*64 + q*8);
      B1.u = *(const uint4*)(msgW + (size_t)(nt*16 + lc)*64 + 32 + q*8);
      f32x4 am = {0,0,0,0};
      am = __builtin_amdgcn_mfma_f32_16x16x32_bf16(A0.v, B0.v, am, 0,0,0);
      am = __builtin_amdgcn_mfma_f32_16x16x32_bf16(A1.v, B1.v, am, 0,0,0);
      float bv = b2f(msgb[nt*16 + lc]);
      #pragma unroll
      for (int rg=0; rg<4; rg++){
        int rw = rt*16 + q*4 + rg;
        float v = am[rg] + bv;
        if (sdeg[rw] == 0) v = 0.f;
        smsg[rw][nt*16 + lc] = f2b(v);
      }
    }
  }
  __syncthreads();
  // ---- gi (waves 0-5: nt=w, both rt) / gh (waves 6-7: rt=w-6, nt 0..5) ----
  {
    float* sgi = (float*)uni;                               // [32][100]
    float* sgh = (float*)(uni + 12800);                     // [32][100]
    if (w < 6){
      int nt = w;
      f32x4 g0 = {0,0,0,0}, g1 = {0,0,0,0};
      #pragma unroll
      for (int ks=0; ks<8; ks++){
        union { uint4 u; bf16x8 v; } A0, A1, B;
        B.u  = *(const uint4*)(wih + (size_t)(nt*16 + lc)*256 + ks*32 + q*8);
        A0.u = *(const uint4*)&smsg[lc][ks*32 + q*8];
        A1.u = *(const uint4*)&smsg[16 + lc][ks*32 + q*8];
        g0 = __builtin_amdgcn_mfma_f32_16x16x32_bf16(A0.v, B.v, g0, 0,0,0);
        g1 = __builtin_amdgcn_mfma_f32_16x16x32_bf16(A1.v, B.v, g1, 0,0,0);
      }
      #pragma unroll
      for (int rg=0; rg<4; rg++){
        sgi[(q*4+rg)*100      + nt*16 + lc] = g0[rg];
        sgi[(16+q*4+rg)*100   + nt*16 + lc] = g1[rg];
      }
    } else {
      int rt = w - 6;
      union { uint4 u; bf16x8 v; } A;
      A.u = *(const uint4*)&sA[rt*16 + lc][q*8];
      #pragma unroll
      for (int nt=0; nt<6; nt++){
        union { uint4 u; bf16x8 v; } B;
        B.u = *(const uint4*)(whh + (size_t)(nt*16 + lc)*32 + q*8);
        f32x4 hh = {0,0,0,0};
        hh = __builtin_amdgcn_mfma_f32_16x16x32_bf16(A.v, B.v, hh, 0,0,0);
        #pragma unroll
        for (int rg=0; rg<4; rg++)
          sgh[(rt*16 + q*4+rg)*100 + nt*16 + lc] = hh[rg];
      }
    }
  }
  __syncthreads();
  // ---- GRU elementwise + hfragOut write (r4-verified pairing) ----
  {
    const float* sgi = (const float*)uni;
    const float* sgh = (const float*)(uni + 12800);
    float ir0 = sgi[r0*100 + cl]    + b2f(bih[cl]),    hr0 = sgh[r0*100 + cl]    + b2f(bhh[cl]);
    float iz0 = sgi[r0*100 + 32+cl] + b2f(bih[32+cl]), hz0 = sgh[r0*100 + 32+cl] + b2f(bhh[32+cl]);
    float in0 = sgi[r0*100 + 64+cl] + b2f(bih[64+cl]), hn0 = sgh[r0*100 + 64+cl] + b2f(bhh[64+cl]);
    float ir1 = sgi[r0*100 + 16+cl] + b2f(bih[16+cl]), hr1 = sgh[r0*100 + 16+cl] + b2f(bhh[16+cl]);
    float iz1 = sgi[r0*100 + 48+cl] + b2f(bih[48+cl]), hz1 = sgh[r0*100 + 48+cl] + b2f(bhh[48+cl]);
    float in1 = sgi[r0*100 + 80+cl] + b2f(bih[80+cl]), hn1 = sgh[r0*100 + 80+cl] + b2f(bhh[80+cl]);
    float rr0 = fsig(ir0 + hr0), zz0 = fsig(iz0 + hz0);
    float rr1 = fsig(ir1 + hr1), zz1 = fsig(iz1 + hz1);
    float nn0 = ftanh(in0 + rr0*hn0);
    float nn1 = ftanh(in1 + rr1*hn1);
    h0 = (1.f - zz0)*nn0 + zz0*h0;
    h1 = (1.f - zz1)*nn1 + zz1*h1;
    hf32[r*32 + cl]      = h0;
    hf32[r*32 + 16 + cl] = h1;
    unsigned int m0 = f2b(h0), m1 = f2b(h1);
    if (!last){
      unsigned int p0 = (unsigned int)__shfl_xor((int)m0, 16);
      unsigned int p1 = (unsigned int)__shfl_xor((int)m1, 16);
      if ((r & 1) == 0){
        int ks32 = r >> 5;
        int Lf = ((r >> 3) & 3)*16 + cl;
        int pidx = (r & 7) >> 1;
        hfragOut[((ks32*2 + 0)*64 + Lf)*4 + pidx] = m0 | (p0 << 16);
        hfragOut[((ks32*2 + 1)*64 + Lf)*4 + pidx] = m1 | (p1 << 16);
      }
    } else {
      if (isb){ out16[r*32 + cl] = (unsigned short)m0; out16[r*32 + 16 + cl] = (unsigned short)m1; }
      else    { out32[r*32 + cl] = h0; out32[r*32 + 16 + cl] = h1; }
      int gb = bidx[r];
      atomicAdd(seg + gb*32 + cl, h0);
      atomicAdd(seg + gb*32 + 16 + cl, h1);
      if (cl == 0) atomicAdd(cnt + gb, 1.f);
    }
  }
}

__global__ void k_pool(const float* __restrict__ seg, const float* __restrict__ cnt,
                       const unsigned short* __restrict__ pw, const unsigned short* __restrict__ pb,
                       const int* __restrict__ flag,
                       unsigned short* __restrict__ outG16, float* __restrict__ outG32){
  int g = blockIdx.x, o = threadIdx.x;
  float cv = cnt[g];
  float ic = cv > 0.f ? 1.f/cv : 0.f;
  float s = 0.f;
  #pragma unroll
  for (int c=0;c<32;c++) s += seg[g*32+c]*ic*b2f(pw[o*32+c]);
  s += b2f(pb[o]);
  if (flag[0]) outG16[g*256 + o] = f2b(s);
  else         outG32[g*256 + o] = s;
}

extern "C" void kernel_launch(void* const* d_in, const int* in_sizes, int n_in,
                              void* d_out, int out_size, void* d_ws, size_t ws_size,
                              hipStream_t stream){
  const int* af   = (const int*)d_in[0];
  const int* bft  = (const int*)d_in[1];
  const int* adj  = (const int*)d_in[2];
  const int* bidx = (const int*)d_in[3];

  char* ws = (char*)d_ws;                                    // ~11.5 MB total
  unsigned int*   mask3  = (unsigned int*)(ws + 0);          // 8 MB
  unsigned int*   hfrag0 = (unsigned int*)(ws + 8388608);    // 512 KB
  unsigned int*   hfrag1 = (unsigned int*)(ws + 8912896);    // 512 KB
  float*          hf32   = (float*)(ws + 9437184);           // 1 MB
  int*            deg    = (int*)(ws + 10485760);            // 32 KB
  float*          seg    = (float*)(ws + 10518528);          // 32 KB
  float*          cnt    = (float*)(ws + 10551296);          // 1 KB
  int*            flag   = (int*)(ws + 10552320);            // 64 B
  unsigned short* cw     = (unsigned short*)(ws + 10552384); // 906 KB canonical bf16 weights

  unsigned short* o16 = (unsigned short*)d_out;
  float*          o32 = (float*)d_out;

  k_prep<<<1803, 256, 0, stream>>>(d_in[6], d_in[7], d_in[8], d_in[9], d_in[10],
                                   d_in[11], d_in[12], d_in[13],
                                   (const unsigned short*)d_in[4],
                                   cw, deg, seg, cnt, flag);
  k_pack<<<8192, 256, 0, stream>>>(adj, mask3, deg);
  k_be<<<2560, 512, 0, stream>>>(af, d_in[4], bft, d_in[5], flag,
                                 hf32, (uint4*)hfrag0,
                                 o16 + 262144, o32 + 262144);

  for (int d = 0; d < 10; d++){
    const uint4*  hin  = (const uint4*)((d & 1) ? hfrag1 : hfrag0);
    unsigned int* hout = (d & 1) ? hfrag0 : hfrag1;
    k_layer<<<256, 512, 0, stream>>>(mask3, hin, hout, hf32, deg,
                                     cw + (size_t)d*16384,        cw + 163840 + d*256,
                                     cw + 166400 + (size_t)d*24576, cw + 412160 + d*3072,
                                     cw + 442880 + d*96,          cw + 443840 + d*96,
                                     bidx, seg, cnt, o16, o32, flag, (d == 9) ? 1 : 0);
  }
  k_pool<<<256, 256, 0, stream>>>(seg, cnt, cw + 444800, cw + 452992, flag,
                                  o16 + 1310720, o32 + 1310720);
}